// Round 4
// baseline (830.625 us; speedup 1.0000x reference)
//
#include <hip/hip_runtime.h>
#include <math.h>

#define N_EDGES   1048576
#define N_SEG     131072        // 32768 centers * 4 species
#define N_BUCKET  1024          // bucket = seg >> 7 (128 segs / bucket)
#define SEG_PER_B 128
#define N_BASIS   12
// out[c*512 + L*32 + s*8 + n], L in [0,16)

// ---------------- workspace layout ----------------
#define WS_COUNTS   0                       // int[1024]
#define WS_OFFSETS  4096                    // int[1024]
#define WS_CURSORS  8192                    // int[1024]
#define WS_SORTED   12288                   // float4[1048576]  (16 MB)
#define WS_NEEDED   (12288 + 16777216)

__device__ __forceinline__ void compute_edge(float x, float y, float z,
                                             float* __restrict__ ph,   // 12, scaled by NORM/r
                                             float* __restrict__ sh)   // 16
{
    const float r2    = fmaf(x, x, fmaf(y, y, z * z)) + 1e-12f;
    const float inv_r = rsqrtf(r2);
    const float r     = r2 * inv_r;
    x *= inv_r; y *= inv_r; z *= inv_r;

    const float t = 0.6283185307179586f * r;   // pi/5 * r
    float s1, c1;
    __sincosf(t, &s1, &c1);
    const float twoc = 2.0f * c1;
    const float scale = 0.17677669529663687f * inv_r;  // (1/sqrt(32)) / r
    float skm1 = 0.0f, sk = s1;
    #pragma unroll
    for (int b = 0; b < N_BASIS; ++b) {
        ph[b] = sk * scale;
        const float nxt = fmaf(twoc, sk, -skm1);
        skm1 = sk; sk = nxt;
    }

    const float x2 = x * x, y2 = y * y, z2 = z * z;
    sh[0]  = 0.28209479177387814f;
    sh[1]  = 0.4886025119029199f * y;
    sh[2]  = 0.4886025119029199f * z;
    sh[3]  = 0.4886025119029199f * x;
    sh[4]  = 1.0925484305920792f * x * y;
    sh[5]  = 1.0925484305920792f * y * z;
    sh[6]  = 0.31539156525252005f * (3.0f * z2 - 1.0f);
    sh[7]  = 1.0925484305920792f * x * z;
    sh[8]  = 0.5462742152960396f * (x2 - y2);
    sh[9]  = 0.5900435899266435f * y * (3.0f * x2 - y2);
    sh[10] = 2.890611442640554f  * x * y * z;
    sh[11] = 0.4570457994644658f * y * (5.0f * z2 - 1.0f);
    sh[12] = 0.3731763325901154f * (5.0f * z2 * z - 3.0f * z);
    sh[13] = 0.4570457994644658f * x * (5.0f * z2 - 1.0f);
    sh[14] = 1.445305721320277f  * z * (x2 - y2);
    sh[15] = 0.5900435899266435f * x * (x2 - y2);
}

// ---------- A1: coarse histogram (LDS-aggregated) ----------
__global__ __launch_bounds__(256) void hist_kernel(
    const int* __restrict__ cidx, const int* __restrict__ sidx,
    int* __restrict__ counts)
{
    __shared__ int h[N_BUCKET];
    const int t = threadIdx.x;
    #pragma unroll
    for (int i = t; i < N_BUCKET; i += 256) h[i] = 0;
    __syncthreads();
    const int base = blockIdx.x * 4096;
    #pragma unroll
    for (int k = 0; k < 16; ++k) {
        const int e = base + k * 256 + t;
        const int seg = (cidx[e] << 2) | sidx[e];
        atomicAdd(&h[seg >> 7], 1);
    }
    __syncthreads();
    #pragma unroll
    for (int i = t; i < N_BUCKET; i += 256)
        if (h[i]) atomicAdd(&counts[i], h[i]);
}

// ---------- scan over 1024 bucket counts (one block) ----------
__global__ __launch_bounds__(1024) void scan_kernel(
    const int* __restrict__ counts, int* __restrict__ offsets,
    int* __restrict__ cursors)
{
    __shared__ int tmp[N_BUCKET];
    const int t = threadIdx.x;
    const int orig = counts[t];
    tmp[t] = orig;
    __syncthreads();
    #pragma unroll
    for (int d = 1; d < N_BUCKET; d <<= 1) {
        const int v = (t >= d) ? tmp[t - d] : 0;
        __syncthreads();
        tmp[t] += v;
        __syncthreads();
    }
    const int off = tmp[t] - orig;
    offsets[t] = off;
    cursors[t] = off;
}

// ---------- A2: coarse partition, 8192 edges/block (chunks avg 8 edges = 128B) ----------
__global__ __launch_bounds__(256) void partition_kernel(
    const float* __restrict__ vectors,
    const int* __restrict__ cidx, const int* __restrict__ sidx,
    int* __restrict__ cursors, float4* __restrict__ sorted)
{
    __shared__ int bhist[N_BUCKET];
    __shared__ int bbase[N_BUCKET];
    __shared__ int lcnt[N_BUCKET];
    const int t = threadIdx.x;
    #pragma unroll
    for (int i = t; i < N_BUCKET; i += 256) bhist[i] = 0;
    __syncthreads();

    const int base = blockIdx.x * 8192;
    int segs[32];
    #pragma unroll
    for (int k = 0; k < 32; ++k) {
        const int e = base + k * 256 + t;
        segs[k] = (cidx[e] << 2) | sidx[e];
        atomicAdd(&bhist[segs[k] >> 7], 1);
    }
    __syncthreads();

    // reserve one contiguous chunk per bucket for this block
    #pragma unroll
    for (int i = t; i < N_BUCKET; i += 256) {
        const int c = bhist[i];
        if (c) bbase[i] = atomicAdd(&cursors[i], c);
        lcnt[i] = 0;
    }
    __syncthreads();

    #pragma unroll
    for (int k = 0; k < 32; ++k) {
        const int e = base + k * 256 + t;
        const int seg = segs[k];
        const int bkt = seg >> 7;
        const int pos = bbase[bkt] + atomicAdd(&lcnt[bkt], 1);
        sorted[pos] = make_float4(vectors[3 * e], vectors[3 * e + 1],
                                  vectors[3 * e + 2],
                                  __int_as_float(seg & (SEG_PER_B - 1)));
    }
}

// ---------- B: edge-parallel compute + LDS atomic tile; one bucket per block ----------
// tile layout (XOR bank swizzle): element (sl, k) at word  sl*128 + (k ^ (sl & 31))
// -> exactly 64 KB, bank = (k%32) ^ (sl&31): random sl spreads lanes over all banks.
__global__ __launch_bounds__(512) void compute_kernel(
    const float4* __restrict__ sorted,
    const int* __restrict__ offsets, const int* __restrict__ counts,
    const float* __restrict__ rw,    // (4,12,8) — read via uniform (scalar-cache) loads
    float* __restrict__ out)
{
    __shared__ float tile[SEG_PER_B * 128];    // 65536 B
    const int t = threadIdx.x;
    const int b = blockIdx.x;

    for (int i = t; i < SEG_PER_B * 128; i += 512) tile[i] = 0.0f;
    __syncthreads();

    const int off = offsets[b];
    const int cnt = counts[b];

    for (int i = t; i < cnt; i += 512) {
        const float4 v = sorted[off + i];
        const int sl = __float_as_int(v.w);
        float ph[N_BASIS], sh[16];
        compute_edge(v.x, v.y, v.z, ph, sh);

        float* tb = &tile[sl * 128];
        const int c = sl & 31;

        #pragma unroll
        for (int l = 0; l < 4; ++l) {
            const int L0 = l * l;              // SH_SPLITS start: 0,1,4,9
            const int ml = 2 * l + 1;
            #pragma unroll
            for (int n = 0; n < 8; ++n) {
                float rad = 0.0f;
                #pragma unroll
                for (int bb = 0; bb < N_BASIS; ++bb)
                    rad = fmaf(ph[bb], rw[(l * N_BASIS + bb) * 8 + n], rad);
                #pragma unroll
                for (int m = 0; m < ml; ++m) {
                    const int k = (L0 + m) * 8 + n;
                    atomicAdd(&tb[k ^ c], sh[L0 + m] * rad);
                }
            }
        }
    }
    __syncthreads();

    // flush tile -> out. bucket's out region is contiguous: out + b*16384, 16384 floats
    float* ob = out + (size_t)b * 16384;
    for (int q = t; q < 4096; q += 512) {
        const int j  = q * 4;                  // j..j+3: same sl, same L, n0..n0+3
        const int sl = ((j >> 9) << 2) | ((j >> 3) & 3);
        const int k  = ((j >> 5) & 15) * 8 + (j & 7);
        const float* tp = &tile[sl * 128];
        const int c = sl & 31;
        float4 w;
        w.x = tp[(k + 0) ^ c];
        w.y = tp[(k + 1) ^ c];
        w.z = tp[(k + 2) ^ c];
        w.w = tp[(k + 3) ^ c];
        ((float4*)ob)[q] = w;
    }
}

// ---------- fallback: atomic kernel (used only if ws too small) ----------
__global__ __launch_bounds__(256) void atomic_kernel(
    const float* __restrict__ vectors, const float* __restrict__ rw,
    const int* __restrict__ cidx, const int* __restrict__ sidx,
    float* __restrict__ out)
{
    const int e = blockIdx.x * 256 + threadIdx.x;
    if (e >= N_EDGES) return;
    float ph[N_BASIS], sh[16];
    compute_edge(vectors[3*e], vectors[3*e+1], vectors[3*e+2], ph, sh);
    float* op = out + (size_t)cidx[e] * 512 + sidx[e] * 8;
    for (int l = 0; l < 4; ++l) {
        const int L0 = l * l;
        const int ml = 2 * l + 1;
        for (int n = 0; n < 8; ++n) {
            float rad = 0.0f;
            for (int b = 0; b < N_BASIS; ++b)
                rad = fmaf(ph[b], rw[(l * N_BASIS + b) * 8 + n], rad);
            for (int m = 0; m < ml; ++m)
                atomicAdd(op + (L0 + m) * 32 + n, sh[L0 + m] * rad);
        }
    }
}

extern "C" void kernel_launch(void* const* d_in, const int* in_sizes, int n_in,
                              void* d_out, int out_size, void* d_ws, size_t ws_size,
                              hipStream_t stream) {
    const float* vectors = (const float*)d_in[0];
    const float* rw      = (const float*)d_in[1];
    const int*   cidx    = (const int*)d_in[2];
    const int*   sidx    = (const int*)d_in[3];
    float*       out     = (float*)d_out;

    if (ws_size < (size_t)WS_NEEDED) {
        hipMemsetAsync(out, 0, (size_t)out_size * sizeof(float), stream);
        hipLaunchKernelGGL(atomic_kernel, dim3(N_EDGES / 256), dim3(256), 0, stream,
                           vectors, rw, cidx, sidx, out);
        return;
    }

    char* ws = (char*)d_ws;
    int*    counts  = (int*)(ws + WS_COUNTS);
    int*    offsets = (int*)(ws + WS_OFFSETS);
    int*    cursors = (int*)(ws + WS_CURSORS);
    float4* sorted  = (float4*)(ws + WS_SORTED);

    hipMemsetAsync(counts, 0, N_BUCKET * sizeof(int), stream);

    hipLaunchKernelGGL(hist_kernel,      dim3(N_EDGES / 4096), dim3(256),  0, stream, cidx, sidx, counts);
    hipLaunchKernelGGL(scan_kernel,      dim3(1),              dim3(1024), 0, stream, counts, offsets, cursors);
    hipLaunchKernelGGL(partition_kernel, dim3(N_EDGES / 8192), dim3(256),  0, stream, vectors, cidx, sidx, cursors, sorted);
    hipLaunchKernelGGL(compute_kernel,   dim3(N_BUCKET),       dim3(512),  0, stream, sorted, offsets, counts, rw, out);
}

// Round 5
// 169.409 us; speedup vs baseline: 4.9031x; 4.9031x over previous
//
#include <hip/hip_runtime.h>
#include <math.h>

#define N_EDGES   1048576
#define N_BUCKET  1024          // bucket = seg >> 7 (128 segs / bucket)
#define SEG_PER_B 128
#define N_BASIS   12
#define CAP       2048          // per-bucket edge capacity (Poisson mean 1024, max~1150)
// out[c*512 + L*32 + s*8 + n], L in [0,16)
// rec = (sl << 20) | edge_id   (sl = seg & 127, edge_id < 2^20)

#define WS_COUNTS   0                       // int[1024]
#define WS_OFFSETS  4096                    // int[1024]
#define WS_CURSORS  8192                    // int[1024]
#define WS_SORTED   12288                   // u32[1048576]  (4 MB)
#define WS_NEEDED   (12288 + 4194304)

__device__ __forceinline__ void compute_edge(float x, float y, float z,
                                             float* __restrict__ ph,   // 12, scaled by NORM/r
                                             float* __restrict__ sh)   // 16
{
    const float r2    = fmaf(x, x, fmaf(y, y, z * z)) + 1e-12f;
    const float inv_r = rsqrtf(r2);
    const float r     = r2 * inv_r;
    x *= inv_r; y *= inv_r; z *= inv_r;

    const float t = 0.6283185307179586f * r;   // pi/5 * r
    float s1, c1;
    __sincosf(t, &s1, &c1);
    const float twoc = 2.0f * c1;
    const float scale = 0.17677669529663687f * inv_r;  // (1/sqrt(32)) / r
    float skm1 = 0.0f, sk = s1;
    #pragma unroll
    for (int b = 0; b < N_BASIS; ++b) {
        ph[b] = sk * scale;
        const float nxt = fmaf(twoc, sk, -skm1);
        skm1 = sk; sk = nxt;
    }

    const float x2 = x * x, y2 = y * y, z2 = z * z;
    sh[0]  = 0.28209479177387814f;
    sh[1]  = 0.4886025119029199f * y;
    sh[2]  = 0.4886025119029199f * z;
    sh[3]  = 0.4886025119029199f * x;
    sh[4]  = 1.0925484305920792f * x * y;
    sh[5]  = 1.0925484305920792f * y * z;
    sh[6]  = 0.31539156525252005f * (3.0f * z2 - 1.0f);
    sh[7]  = 1.0925484305920792f * x * z;
    sh[8]  = 0.5462742152960396f * (x2 - y2);
    sh[9]  = 0.5900435899266435f * y * (3.0f * x2 - y2);
    sh[10] = 2.890611442640554f  * x * y * z;
    sh[11] = 0.4570457994644658f * y * (5.0f * z2 - 1.0f);
    sh[12] = 0.3731763325901154f * (5.0f * z2 * z - 3.0f * z);
    sh[13] = 0.4570457994644658f * x * (5.0f * z2 - 1.0f);
    sh[14] = 1.445305721320277f  * z * (x2 - y2);
    sh[15] = 0.5900435899266435f * x * (x2 - y2);
}

__device__ __forceinline__ void flush_seg(const float* __restrict__ acc,
                                          int b, int sl, int n,
                                          float* __restrict__ out)
{
    const int seg = b * SEG_PER_B + sl;
    float* op = out + (size_t)(seg >> 2) * 512 + (seg & 3) * 8 + n;
    #pragma unroll
    for (int L = 0; L < 16; ++L) op[L * 32] = acc[L];
}

// ---------- A1: coarse histogram (LDS-aggregated) ----------
__global__ __launch_bounds__(256) void hist_kernel(
    const int* __restrict__ cidx, const int* __restrict__ sidx,
    int* __restrict__ counts)
{
    __shared__ int h[N_BUCKET];
    const int t = threadIdx.x;
    #pragma unroll
    for (int i = t; i < N_BUCKET; i += 256) h[i] = 0;
    __syncthreads();
    const int base = blockIdx.x * 4096;
    #pragma unroll
    for (int k = 0; k < 16; ++k) {
        const int e = base + k * 256 + t;
        const int seg = (cidx[e] << 2) | sidx[e];
        atomicAdd(&h[seg >> 7], 1);
    }
    __syncthreads();
    #pragma unroll
    for (int i = t; i < N_BUCKET; i += 256)
        if (h[i]) atomicAdd(&counts[i], h[i]);
}

// ---------- scan over 1024 bucket counts (one block) ----------
__global__ __launch_bounds__(1024) void scan_kernel(
    const int* __restrict__ counts, int* __restrict__ offsets,
    int* __restrict__ cursors)
{
    __shared__ int tmp[N_BUCKET];
    const int t = threadIdx.x;
    const int orig = counts[t];
    tmp[t] = orig;
    __syncthreads();
    #pragma unroll
    for (int d = 1; d < N_BUCKET; d <<= 1) {
        const int v = (t >= d) ? tmp[t - d] : 0;
        __syncthreads();
        tmp[t] += v;
        __syncthreads();
    }
    const int off = tmp[t] - orig;
    offsets[t] = off;
    cursors[t] = off;
}

// ---------- A2: coarse partition; writes 4B recs only ----------
__global__ __launch_bounds__(256) void partition_kernel(
    const int* __restrict__ cidx, const int* __restrict__ sidx,
    int* __restrict__ cursors, unsigned int* __restrict__ sorted_rec)
{
    __shared__ int bhist[N_BUCKET];
    __shared__ int bbase[N_BUCKET];
    __shared__ int lcnt[N_BUCKET];
    const int t = threadIdx.x;
    #pragma unroll
    for (int i = t; i < N_BUCKET; i += 256) bhist[i] = 0;
    __syncthreads();

    const int base = blockIdx.x * 4096;
    int segs[16];
    #pragma unroll
    for (int k = 0; k < 16; ++k) {
        const int e = base + k * 256 + t;
        segs[k] = (cidx[e] << 2) | sidx[e];
        atomicAdd(&bhist[segs[k] >> 7], 1);
    }
    __syncthreads();

    #pragma unroll
    for (int i = t; i < N_BUCKET; i += 256) {
        const int c = bhist[i];
        if (c) bbase[i] = atomicAdd(&cursors[i], c);
        lcnt[i] = 0;
    }
    __syncthreads();

    #pragma unroll
    for (int k = 0; k < 16; ++k) {
        const int e = base + k * 256 + t;
        const int seg = segs[k];
        const int bkt = seg >> 7;
        const int pos = bbase[bkt] + atomicAdd(&lcnt[bkt], 1);
        sorted_rec[pos] = ((unsigned)(seg & 127) << 20) | (unsigned)e;
    }
}

// ---------- B: per-bucket sort + fused per-group segment scan ----------
__global__ __launch_bounds__(256) void compute_kernel(
    const unsigned int* __restrict__ sorted_rec,
    const int* __restrict__ offsets, const int* __restrict__ counts,
    const float* __restrict__ vectors,
    const float* __restrict__ rw,    // (4,12,8)
    float* __restrict__ out)
{
    __shared__ float4 pay[CAP];                 // 32 KB
    __shared__ int shist[SEG_PER_B];
    __shared__ int soff[SEG_PER_B];
    __shared__ int scur[SEG_PER_B];

    const int t = threadIdx.x;
    const int b = blockIdx.x;
    const int n = t & 7;                        // radial index owned by this lane
    const int g = t >> 3;                       // group 0..31; owns segments 4g..4g+3

    // per-lane W slice: Wn[l][bb] = rw[(l*12+bb)*8 + n]  (48 VGPRs, loaded once)
    float Wn[4][N_BASIS];
    #pragma unroll
    for (int l = 0; l < 4; ++l)
        #pragma unroll
        for (int bb = 0; bb < N_BASIS; ++bb)
            Wn[l][bb] = rw[(l * N_BASIS + bb) * 8 + n];

    const int off = offsets[b];
    const int cnt = counts[b];

    if (cnt > CAP) {
        // correctness-only slow path (never taken for Poisson(1024) buckets)
        #pragma unroll 1
        for (int k = 0; k < 4; ++k) {
            const int sl = g * 4 + k;
            float acc[16];
            #pragma unroll
            for (int L = 0; L < 16; ++L) acc[L] = 0.0f;
            for (int j = 0; j < cnt; ++j) {
                const unsigned rec = sorted_rec[off + j];
                if ((int)(rec >> 20) != sl) continue;
                const int eid = rec & 0xFFFFF;
                float ph[N_BASIS], sh[16];
                compute_edge(vectors[3*eid], vectors[3*eid+1], vectors[3*eid+2], ph, sh);
                float rad[4];
                #pragma unroll
                for (int l = 0; l < 4; ++l) {
                    float a = 0.0f;
                    #pragma unroll
                    for (int bb = 0; bb < N_BASIS; ++bb)
                        a = fmaf(ph[bb], Wn[l][bb], a);
                    rad[l] = a;
                }
                #pragma unroll
                for (int L = 0; L < 16; ++L) {
                    const int l = (L == 0) ? 0 : (L < 4) ? 1 : (L < 9) ? 2 : 3;
                    acc[L] = fmaf(sh[L], rad[l], acc[L]);
                }
            }
            flush_seg(acc, b, sl, n, out);
        }
        return;
    }

    if (t < SEG_PER_B) shist[t] = 0;
    __syncthreads();

    // stage recs in registers + histogram by local segment
    unsigned recs[8];
    const int iters = (cnt + 255) >> 8;         // <= 8
    #pragma unroll
    for (int it = 0; it < 8; ++it) {
        const int i = it * 256 + t;
        if (it < iters && i < cnt) {
            recs[it] = sorted_rec[off + i];
            atomicAdd(&shist[recs[it] >> 20], 1);
        }
    }
    __syncthreads();

    // exclusive scan of shist (128 entries)
    if (t < SEG_PER_B) soff[t] = shist[t];
    __syncthreads();
    #pragma unroll
    for (int d = 1; d < SEG_PER_B; d <<= 1) {
        int v = 0;
        if (t >= d && t < SEG_PER_B) v = soff[t - d];
        __syncthreads();
        if (t < SEG_PER_B) soff[t] += v;
        __syncthreads();
    }
    if (t < SEG_PER_B) {
        const int ex = soff[t] - shist[t];
        soff[t] = ex;
        scur[t] = ex;
    }
    __syncthreads();

    // place: rank + gather xyz from L2/L3-resident vectors
    #pragma unroll
    for (int it = 0; it < 8; ++it) {
        const int i = it * 256 + t;
        if (it < iters && i < cnt) {
            const unsigned rec = recs[it];
            const int sl  = rec >> 20;
            const int eid = rec & 0xFFFFF;
            const int r = atomicAdd(&scur[sl], 1);
            pay[r] = make_float4(vectors[3 * eid], vectors[3 * eid + 1],
                                 vectors[3 * eid + 2], __int_as_float(sl));
        }
    }
    __syncthreads();

    // fused scan: group g walks the concatenated edges of segments 4g..4g+3
    const int s0 = g * 4;
    const int js = soff[s0];
    const int je = (s0 + 4 < SEG_PER_B) ? soff[s0 + 4] : cnt;

    int cur = -1;
    float acc[16];
    #pragma unroll
    for (int L = 0; L < 16; ++L) acc[L] = 0.0f;

    for (int j = js; j < je; ++j) {
        const float4 v = pay[j];                // 8-lane broadcast b128
        const int sl = __float_as_int(v.w);
        if (sl != cur) {
            if (cur >= 0) {
                flush_seg(acc, b, cur, n, out);
                #pragma unroll
                for (int L = 0; L < 16; ++L) acc[L] = 0.0f;
            }
            cur = sl;
        }
        float ph[N_BASIS], sh[16];
        compute_edge(v.x, v.y, v.z, ph, sh);
        float rad[4];
        #pragma unroll
        for (int l = 0; l < 4; ++l) {
            float a = 0.0f;
            #pragma unroll
            for (int bb = 0; bb < N_BASIS; ++bb)
                a = fmaf(ph[bb], Wn[l][bb], a);
            rad[l] = a;
        }
        #pragma unroll
        for (int L = 0; L < 16; ++L) {
            const int l = (L == 0) ? 0 : (L < 4) ? 1 : (L < 9) ? 2 : 3;
            acc[L] = fmaf(sh[L], rad[l], acc[L]);
        }
    }
    if (cur >= 0) flush_seg(acc, b, cur, n, out);

    // zero-fill empty segments (output is poisoned; every element must be written)
    #pragma unroll
    for (int k = 0; k < 4; ++k) {
        const int sl = s0 + k;
        if (shist[sl] == 0) {
            float z[16];
            #pragma unroll
            for (int L = 0; L < 16; ++L) z[L] = 0.0f;
            flush_seg(z, b, sl, n, out);
        }
    }
}

// ---------- fallback: atomic kernel (used only if ws too small) ----------
__global__ __launch_bounds__(256) void atomic_kernel(
    const float* __restrict__ vectors, const float* __restrict__ rw,
    const int* __restrict__ cidx, const int* __restrict__ sidx,
    float* __restrict__ out)
{
    const int e = blockIdx.x * 256 + threadIdx.x;
    if (e >= N_EDGES) return;
    float ph[N_BASIS], sh[16];
    compute_edge(vectors[3*e], vectors[3*e+1], vectors[3*e+2], ph, sh);
    float* op = out + (size_t)cidx[e] * 512 + sidx[e] * 8;
    for (int l = 0; l < 4; ++l) {
        const int L0 = l * l;
        const int ml = 2 * l + 1;
        for (int n = 0; n < 8; ++n) {
            float rad = 0.0f;
            for (int b = 0; b < N_BASIS; ++b)
                rad = fmaf(ph[b], rw[(l * N_BASIS + b) * 8 + n], rad);
            for (int m = 0; m < ml; ++m)
                atomicAdd(op + (L0 + m) * 32 + n, sh[L0 + m] * rad);
        }
    }
}

extern "C" void kernel_launch(void* const* d_in, const int* in_sizes, int n_in,
                              void* d_out, int out_size, void* d_ws, size_t ws_size,
                              hipStream_t stream) {
    const float* vectors = (const float*)d_in[0];
    const float* rw      = (const float*)d_in[1];
    const int*   cidx    = (const int*)d_in[2];
    const int*   sidx    = (const int*)d_in[3];
    float*       out     = (float*)d_out;

    if (ws_size < (size_t)WS_NEEDED) {
        hipMemsetAsync(out, 0, (size_t)out_size * sizeof(float), stream);
        hipLaunchKernelGGL(atomic_kernel, dim3(N_EDGES / 256), dim3(256), 0, stream,
                           vectors, rw, cidx, sidx, out);
        return;
    }

    char* ws = (char*)d_ws;
    int*          counts  = (int*)(ws + WS_COUNTS);
    int*          offsets = (int*)(ws + WS_OFFSETS);
    int*          cursors = (int*)(ws + WS_CURSORS);
    unsigned int* sorted  = (unsigned int*)(ws + WS_SORTED);

    hipMemsetAsync(counts, 0, N_BUCKET * sizeof(int), stream);

    hipLaunchKernelGGL(hist_kernel,      dim3(N_EDGES / 4096), dim3(256),  0, stream, cidx, sidx, counts);
    hipLaunchKernelGGL(scan_kernel,      dim3(1),              dim3(1024), 0, stream, counts, offsets, cursors);
    hipLaunchKernelGGL(partition_kernel, dim3(N_EDGES / 4096), dim3(256),  0, stream, cidx, sidx, cursors, sorted);
    hipLaunchKernelGGL(compute_kernel,   dim3(N_BUCKET),       dim3(256),  0, stream, sorted, offsets, counts, vectors, rw, out);
}